// Round 17
// baseline (278.698 us; speedup 1.0000x reference)
//
#include <hip/hip_runtime.h>
#include <hip/hip_bf16.h>

typedef _Float16 f16x8 __attribute__((ext_vector_type(8)));
typedef float f32x4 __attribute__((ext_vector_type(4)));
typedef unsigned long long ull;

#define UNITS   2048
#define NC      6144
#define TSTEPS  32
#define HSTRIDE 131072     // one h buffer: 64 seqs x 2048 units fp16 (blocked layout)
#define XPB_STRIDE 98304   // per-block xp slice: 64 s x 32 t x 3 gates x 16 u (f16)

__device__ __forceinline__ float sigmoid_f(float v){ return 1.0f/(1.0f+__expf(-v)); }
__device__ __forceinline__ float tanh_f(float v){ return 2.0f/(1.0f+__expf(-2.0f*v)) - 1.0f; }

// ---- prep: cast x to fp16; init ring[0] (blocked [u>>3][s][u&7]); zero flags ----
__global__ __launch_bounds__(256) void prep_misc(
    const float* __restrict__ x, const float* __restrict__ h0,
    _Float16* __restrict__ xh, _Float16* __restrict__ hRing,
    unsigned* __restrict__ bar)
{
  int i = blockIdx.x*256 + threadIdx.x;
  if (i < 640) bar[i] = 0;
  if (i < 524288) xh[i] = (_Float16)x[i];
  if (i < 131072) {
    int s = i >> 11, u = i & 2047;
    float v = h0[((s & 7) << 11) + u];
    hRing[(((u >> 3) << 6) + s)*8 + (u & 7)] = (_Float16)v;
  }
}

// ---- tree barrier, merged root/publication (champion, unchanged) ----
__device__ __forceinline__ void half_barrier(unsigned* bar, int half, int idxInHalf, int t)
{
  __syncthreads();   // compiler emits s_waitcnt vmcnt(0) here: h stores at MALL
  if (threadIdx.x == 0) {
    unsigned* grp  = bar + (half*8 + (idxInHalf & 7))*32;
    unsigned* root = bar + (16 + half)*32;
    unsigned tgt = (unsigned)(t + 1);
    unsigned a = __hip_atomic_fetch_add(grp, 1u, __ATOMIC_RELAXED, __HIP_MEMORY_SCOPE_AGENT) + 1u;
    if (a == tgt*16u)
      __hip_atomic_fetch_add(root, 1u, __ATOMIC_RELAXED, __HIP_MEMORY_SCOPE_AGENT);
    while (__hip_atomic_load(root, __ATOMIC_RELAXED, __HIP_MEMORY_SCOPE_AGENT) < tgt*8u)
      __builtin_amdgcn_s_sleep(1);
  }
  __syncthreads();
  __builtin_amdgcn_fence(__ATOMIC_ACQUIRE, "workgroup");
}

// ---- mega persistent kernel: per-block W/U column-band staging + own-slice xp
//      prefix-GEMM + champion recurrence ----
__global__ __launch_bounds__(512, 2) void gru_mega(
    const float* __restrict__ W, const float* __restrict__ U,
    const float* __restrict__ b, const float* __restrict__ h0,
    const _Float16* __restrict__ xh,
    _Float16* __restrict__ xpb, _Float16* __restrict__ hRing,
    float* __restrict__ ret, float* __restrict__ st, unsigned* __restrict__ bar)
{
  __shared__ __align__(16) float sRed[48*288];   // 55.3 KB; first 24 KB aliased for staging
  char* sStage = (char*)sRed;

  int tid = threadIdx.x;
  int lane = tid & 63, w8 = tid >> 6;       // 8 waves
  int half = blockIdx.x & 1;
  int idxInHalf = blockIdx.x >> 1;
  int u0 = idxInHalf * 16;
  int s0 = half * 32;
  int nl = lane & 15, kg = lane >> 4;
  int redidx = lane*4 + (lane>>3)*4;

  const float* bin  = b;
  const float* brec = b + NC;
  _Float16* myxp = xpb + (size_t)blockIdx.x * XPB_STRIDE;

  // ======== Phase 1: xp prefix-GEMM for this block's 48 cols ========
  {
    float bv[3];
    #pragma unroll
    for (int g = 0; g < 3; ++g) bv[g] = bin[g*2048 + u0 + nl];
    f32x4 acc[2][3];
    #pragma unroll
    for (int rt = 0; rt < 2; ++rt)
      #pragma unroll
      for (int ct = 0; ct < 3; ++ct) acc[rt][ct] = (f32x4){0,0,0,0};

    for (int l = 0; l < 8; ++l) {
      __syncthreads();
      // stage W l-slice [48 cols][256 k] f32 -> f16 LDS, swizzled
      #pragma unroll
      for (int i = 0; i < 6; ++i) {
        int c = tid + i*512;              // 3072 chunks: k = c/12, colq = c%12
        int k = c / 12, colq = c - k*12;
        f32x4 v = *(const f32x4*)(W + (size_t)(l*256 + k)*NC
                                    + (colq>>2)*2048 + u0 + (colq&3)*4);
        #pragma unroll
        for (int j = 0; j < 4; ++j) {
          int cl = colq*4 + j;
          int off = (cl*512 + k*2) ^ ((cl&7)<<4);
          *(_Float16*)(sStage + off) = (_Float16)v[j];
        }
      }
      __syncthreads();
      #pragma unroll
      for (int ks = 0; ks < 8; ++ks) {
        f16x8 a[2];
        #pragma unroll
        for (int rt = 0; rt < 2; ++rt) {
          int rbt = (w8*2 + rt)*16 + nl;
          a[rt] = *(const f16x8*)(xh + ((size_t)rbt*8 + l)*256 + ks*32 + kg*8);
        }
        #pragma unroll
        for (int ct = 0; ct < 3; ++ct) {
          int cl = ct*16 + nl;
          int off = (cl*512 + (ks*32 + kg*8)*2) ^ ((cl&7)<<4);
          f16x8 bf = *(const f16x8*)(sStage + off);
          #pragma unroll
          for (int rt = 0; rt < 2; ++rt)
            acc[rt][ct] = __builtin_amdgcn_mfma_f32_16x16x32_f16(a[rt], bf, acc[rt][ct], 0,0,0);
        }
      }
      // write xp rows for m = l (block-local layout [s][t][gate][16])
      #pragma unroll
      for (int rt = 0; rt < 2; ++rt)
        #pragma unroll
        for (int ct = 0; ct < 3; ++ct)
          #pragma unroll
          for (int r = 0; r < 4; ++r) {
            int rbt = (w8*2 + rt)*16 + kg*4 + r;
            int bb = rbt >> 5, tt = rbt & 31;
            int s = l*8 + bb;
            myxp[((size_t)(s*32 + tt)*3 + ct)*16 + nl] = (_Float16)(acc[rt][ct][r] + bv[ct]);
          }
    }
  }

  // ======== Phase 2: U column-band -> uw regs via per-band LDS transpose ========
  f16x8 uw[3][8];
  for (int band = 0; band < 8; ++band) {
    __syncthreads();
    #pragma unroll
    for (int i = 0; i < 6; ++i) {
      int c = tid + i*512;
      int k = c / 12, colq = c - k*12;
      f32x4 v = *(const f32x4*)(U + (size_t)(band*256 + k)*NC
                                  + (colq>>2)*2048 + u0 + (colq&3)*4);
      #pragma unroll
      for (int j = 0; j < 4; ++j) {
        int cl = colq*4 + j;
        int off = (cl*512 + k*2) ^ ((cl&7)<<4);
        *(_Float16*)(sStage + off) = (_Float16)v[j];
      }
    }
    __syncthreads();
    if (w8 == band) {
      #pragma unroll
      for (int g = 0; g < 3; ++g)
        #pragma unroll
        for (int kk = 0; kk < 8; ++kk) {
          int cl = g*16 + nl;
          int off = (cl*512 + (kk*32 + kg*8)*2) ^ ((cl&7)<<4);
          uw[g][kk] = *(const f16x8*)(sStage + off);
        }
    }
  }
  #pragma unroll
  for (int g = 0; g < 3; ++g)
    #pragma unroll
    for (int kk = 0; kk < 8; ++kk)
      asm volatile("" : "+v"(uw[g][kk]));
  __syncthreads();

  // ======== Phase 3: recurrence (champion, xp source changed only) ========
  int kq = w8;
  int s_local = tid >> 4, u_local = tid & 15;
  int sg = s0 + s_local;
  int u  = u0 + u_local;
  int mE = s_local >> 4, kgE = (s_local >> 2) & 3, rE = s_local & 3;
  int laneE = kgE*16 + u_local;
  int ridxE = laneE*4 + (laneE>>3)*4 + rE;
  int mm = u0 >> 8;

  float bz = brec[u], br = brec[2048+u], bh = brec[4096+u];
  float hprev = h0[((sg & 7) << 11) + u];

  for (int t = 0; t < TSTEPS; ++t) {
    const _Float16* hc = hRing + (size_t)t*HSTRIDE;
    _Float16*       hn = hRing + (size_t)(t+1)*HSTRIDE;

    // xp(t) from block-local slice; latency hides under the MFMA chain
    const _Float16* xrow = myxp + (size_t)(sg*32 + t)*48;
    float xz  = (float)xrow[u_local];
    float xr  = (float)xrow[16 + u_local];
    float xhv = (float)xrow[32 + u_local];

    f32x4 a0z={0,0,0,0}, a0r={0,0,0,0}, a0h={0,0,0,0};
    f32x4 a1z={0,0,0,0}, a1r={0,0,0,0}, a1h={0,0,0,0};
    const _Float16* Ab = hc + (size_t)(((kq*32 + kg)*64) + s0 + nl)*8;
    #pragma unroll
    for (int kk = 0; kk < 8; ++kk) {
      f16x8 av0 = *(const f16x8*)(Ab + kk*2048);
      f16x8 av1 = *(const f16x8*)(Ab + kk*2048 + 128);
      a0z = __builtin_amdgcn_mfma_f32_16x16x32_f16(av0, uw[0][kk], a0z, 0,0,0);
      a1z = __builtin_amdgcn_mfma_f32_16x16x32_f16(av1, uw[0][kk], a1z, 0,0,0);
      a0r = __builtin_amdgcn_mfma_f32_16x16x32_f16(av0, uw[1][kk], a0r, 0,0,0);
      a1r = __builtin_amdgcn_mfma_f32_16x16x32_f16(av1, uw[1][kk], a1r, 0,0,0);
      a0h = __builtin_amdgcn_mfma_f32_16x16x32_f16(av0, uw[2][kk], a0h, 0,0,0);
      a1h = __builtin_amdgcn_mfma_f32_16x16x32_f16(av1, uw[2][kk], a1h, 0,0,0);
    }

    {
      float* rp0 = &sRed[((kq*2 + 0)*3)*288 + redidx];
      *(f32x4*)(rp0)        = a0z;
      *(f32x4*)(rp0 + 288)  = a0r;
      *(f32x4*)(rp0 + 576)  = a0h;
      float* rp1 = &sRed[((kq*2 + 1)*3)*288 + redidx];
      *(f32x4*)(rp1)        = a1z;
      *(f32x4*)(rp1 + 288)  = a1r;
      *(f32x4*)(rp1 + 576)  = a1h;
    }
    __syncthreads();

    {
      float vz = 0.f, vr = 0.f, vh = 0.f;
      #pragma unroll
      for (int q = 0; q < 8; ++q) {
        const float* base = &sRed[((q*2 + mE)*3)*288 + ridxE];
        vz += base[0];
        vr += base[288];
        vh += base[576];
      }
      float z   = sigmoid_f(xz  + vz + bz);
      float rg  = sigmoid_f(xr  + vr + br);
      float hh  = tanh_f(xhv + rg*(vh + bh));
      float hnv = z*hprev + (1.0f - z)*hh;
      hprev = hnv;
      _Float16 hb = (_Float16)hnv;
      __hip_atomic_store((unsigned short*)hn + (size_t)(((u >> 3) << 6) + sg)*8 + (u & 7),
                         __builtin_bit_cast(unsigned short, hb),
                         __ATOMIC_RELAXED, __HIP_MEMORY_SCOPE_AGENT);
      if ((sg >> 3) == mm)
        ret[(size_t)((((sg & 7)*32 + t) << 3) + mm)*256 + (u & 255)] = hnv;
      if (t == 31 && sg >= 56)
        st[(size_t)(sg - 56)*UNITS + u] = hnv;
    }
    if (t < TSTEPS - 1)
      half_barrier(bar, half, idxInHalf, t);
  }
}

extern "C" void kernel_launch(void* const* d_in, const int* in_sizes, int n_in,
                              void* d_out, int out_size, void* d_ws, size_t ws_size,
                              hipStream_t stream) {
  const float* x  = (const float*)d_in[0];
  const float* h0 = (const float*)d_in[1];
  const float* W  = (const float*)d_in[2];
  const float* U  = (const float*)d_in[3];
  const float* b  = (const float*)d_in[4];
  float* ret = (float*)d_out;
  float* st  = ret + 524288;

  char* p = (char*)d_ws;
  _Float16* xh    = (_Float16*)p; p += 1048576;
  _Float16* xpb   = (_Float16*)p; p += 256ull * XPB_STRIDE * 2;  // 50.3 MB
  _Float16* hRing = (_Float16*)p; p += 33ull * HSTRIDE * 2;      // 8.65 MB
  unsigned* bar   = (unsigned*)p; p += 2560;

  prep_misc<<<2048, 256, 0, stream>>>(x, h0, xh, hRing, bar);

  void* args[] = { (void*)&W, (void*)&U, (void*)&b, (void*)&h0, (void*)&xh,
                   (void*)&xpb, (void*)&hRing, (void*)&ret, (void*)&st, (void*)&bar };
  hipLaunchCooperativeKernel((const void*)gru_mega, dim3(256), dim3(512),
                             args, 0, stream);
}